// Round 4
// baseline (1692.036 us; speedup 1.0000x reference)
//
#include <hip/hip_runtime.h>

typedef unsigned short u16;
using f16x8 = __attribute__((ext_vector_type(8))) _Float16;  // 8 fp16 (4 VGPRs)
using f32x4 = __attribute__((ext_vector_type(4))) float;

#define V_N 16384
#define M_N 32768

__device__ __forceinline__ float h2f(u16 u) {
  _Float16 h; __builtin_memcpy(&h, &u, 2); return (float)h;
}
__device__ __forceinline__ u16 f2h(float f) {
  _Float16 h = (_Float16)f; u16 u; __builtin_memcpy(&u, &h, 2); return u;
}

// ---------- prep kernels ----------
// eidx[v*12+t] = sp_flat[t*V + v]  (reshape-scrambled effective neighbor table:
// neigh[b, c*L+t, v] = x[b, c, sp_flat[t*V+v]] because (rem/L)*L + rem%L == rem)
__global__ __launch_bounds__(256) void eidx_k(const int* __restrict__ sp, int* __restrict__ e) {
  int i = blockIdx.x * 256 + threadIdx.x;            // V_N*12
  int v = i / 12, t = i - v * 12;
  e[i] = sp[t * V_N + v];
}

// wp[o][t*256+c] = f2h(w[o][c*12+t])   (l-major K permutation, f32 -> fp16)
__global__ __launch_bounds__(256) void perm_k(const float* __restrict__ w, u16* __restrict__ wp) {
  int i = blockIdx.x * 256 + threadIdx.x;            // 256*3072
  int o = i / 3072, k = i - o * 3072;
  int t = k >> 8, c = k & 255;
  wp[i] = f2h(w[o * 3072 + c * 12 + t]);
}

// flat f32 -> fp16 convert
__global__ __launch_bounds__(256) void cvt_k(const float* __restrict__ w, u16* __restrict__ wb, int n) {
  int i = blockIdx.x * 256 + threadIdx.x;
  if (i < n) wb[i] = f2h(w[i]);
}

// cls2_w (64x128 f32) -> zero-padded 128x128 fp16
__global__ __launch_bounds__(256) void pad_k(const float* __restrict__ w, u16* __restrict__ wp) {
  int i = blockIdx.x * 256 + threadIdx.x;            // 128*128
  wp[i] = (i < 8192) ? f2h(w[i]) : (u16)0;
}

// ---------- encoder block 0 conv (C_in=3, K=36), f32 in -> fp16 out ----------
__global__ __launch_bounds__(256) void enc0_k(const float* __restrict__ verts, const int* __restrict__ e0,
                                              const float* __restrict__ w0, u16* __restrict__ y) {
  __shared__ float xs[32][36];
  int t = threadIdx.x;
  int r0 = blockIdx.x * 32;
  for (int s = t; s < 32 * 12; s += 256) {
    int row = s / 12, tt = s - row * 12;
    int gr = r0 + row;
    int b = gr >> 14, v = gr & (V_N - 1);
    int j = e0[v * 12 + tt];
    const float* p = verts + ((long)b * V_N + j) * 3;
    xs[row][tt]      = p[0];
    xs[row][12 + tt] = p[1];
    xs[row][24 + tt] = p[2];
  }
  __syncthreads();
  float w[36];
  #pragma unroll
  for (int k = 0; k < 36; ++k) w[k] = w0[t * 36 + k];
  for (int row = 0; row < 32; ++row) {
    float a = 0.f;
    #pragma unroll
    for (int k = 0; k < 36; ++k) a += w[k] * xs[row][k];
    y[(long)(r0 + row) * 256 + t] = f2h(a);
  }
}

// ---------- MFMA GEMM: Y[M x Ostore](fp16) = gatherA[M x (L*C)] * Wt^T (+f32 bias) ----------
// Gather: row = b*V + eidx[v*L+l] (eidx!=null) else global row.
// A source = A1 for l==0, A2 for l>=1 (concat trick). Wt: fp16 [o][l*C+c], stride ldw.
__global__ __launch_bounds__(256) void gemm_k(
    const u16* __restrict__ A1, const u16* __restrict__ A2, int lda,
    const int* __restrict__ eidx, int L, int C,
    const u16* __restrict__ Wt, int ldw,
    u16* __restrict__ Yb, const float* __restrict__ bias, int Ostore)
{
  __shared__ __align__(16) u16 lA[128 * 72];   // 144B row stride (odd 16B-vec count)
  __shared__ __align__(16) u16 lB[128 * 72];
  int tid  = threadIdx.x;
  int bm   = blockIdx.x * 128;
  int bn   = blockIdx.y * 128;
  int wave = tid >> 6, lane = tid & 63;
  int wm = (wave & 1) * 64, wn = (wave >> 1) * 64;
  int lr = lane & 15, lq = lane >> 4;

  f32x4 acc[4][4];
  #pragma unroll
  for (int i = 0; i < 4; ++i)
    #pragma unroll
    for (int j = 0; j < 4; ++j) acc[i][j] = (f32x4){0.f, 0.f, 0.f, 0.f};

  for (int l = 0; l < L; ++l) {
    const u16* Ab = (eidx != nullptr || l == 0 || A2 == nullptr) ? A1 : A2;
    long arow[4];
    #pragma unroll
    for (int it = 0; it < 4; ++it) {
      int s = tid + it * 256, r = s >> 3;
      int gr = bm + r;
      if (eidx) {
        int b = gr >> 14, v = gr & (V_N - 1);
        arow[it] = (long)b * V_N + eidx[v * L + l];
      } else {
        arow[it] = gr;
      }
    }
    for (int c0 = 0; c0 < C; c0 += 64) {
      #pragma unroll
      for (int it = 0; it < 4; ++it) {
        int s = tid + it * 256, r = s >> 3, j = s & 7;
        uint4 av = *(const uint4*)(Ab + arow[it] * lda + (c0 + 8 * j));
        *(uint4*)(&lA[r * 72 + j * 8]) = av;
        int orow = bn + r;
        uint4 bv = *(const uint4*)(Wt + (long)orow * ldw + (l * C + c0 + 8 * j));
        *(uint4*)(&lB[r * 72 + j * 8]) = bv;
      }
      __syncthreads();
      #pragma unroll
      for (int ks = 0; ks < 2; ++ks) {
        f16x8 af[4], bfr[4];
        #pragma unroll
        for (int mt = 0; mt < 4; ++mt)
          af[mt] = *(const f16x8*)(&lA[(wm + mt * 16 + lr) * 72 + (ks * 4 + lq) * 8]);
        #pragma unroll
        for (int nt = 0; nt < 4; ++nt)
          bfr[nt] = *(const f16x8*)(&lB[(wn + nt * 16 + lr) * 72 + (ks * 4 + lq) * 8]);
        #pragma unroll
        for (int mt = 0; mt < 4; ++mt)
          #pragma unroll
          for (int nt = 0; nt < 4; ++nt)
            acc[mt][nt] = __builtin_amdgcn_mfma_f32_16x16x32_f16(af[mt], bfr[nt], acc[mt][nt], 0, 0, 0);
      }
      __syncthreads();
    }
  }

  // C/D layout: col=lane&15, row=(lane>>4)*4+reg  [guide m89]
  #pragma unroll
  for (int nt = 0; nt < 4; ++nt) {
    int col = bn + wn + nt * 16 + lr;
    if (col < Ostore) {
      float bv = bias ? bias[col] : 0.f;
      #pragma unroll
      for (int mt = 0; mt < 4; ++mt) {
        #pragma unroll
        for (int rg = 0; rg < 4; ++rg) {
          int row = bm + wm + mt * 16 + lq * 4 + rg;
          Yb[(long)row * Ostore + col] = f2h(acc[mt][nt][rg] + bv);
        }
      }
    }
  }
}

// ---------- BN stats: per-channel sum / sumsq over all M rows (fp16 input) ----------
__global__ void stats_k(const u16* __restrict__ y, float* __restrict__ st, int O) {
  int c = threadIdx.x;
  long r0 = (long)blockIdx.x * 64;
  float s1 = 0.f, s2 = 0.f;
  for (int r = 0; r < 64; ++r) {
    float v = h2f(y[(r0 + r) * O + c]);
    s1 += v; s2 += v * v;
  }
  atomicAdd(&st[c], s1);
  atomicAdd(&st[O + c], s2);
}

// ---------- BN+ReLU (+fp16 residual) (+SE channel sums), fp16 out; g/beta f32 ----------
__global__ void bnrelu_k(const u16* __restrict__ y, const float* __restrict__ st,
                         const float* __restrict__ g, const float* __restrict__ be,
                         const u16* __restrict__ resid, u16* __restrict__ ob,
                         float* __restrict__ ses, int O)
{
  int c = threadIdx.x;
  long r0 = (long)blockIdx.x * 64;
  float mean = st[c] * (1.f / 32768.f);
  float var  = st[O + c] * (1.f / 32768.f) - mean * mean;
  float sc = rsqrtf(fmaxf(var, 0.f) + 1e-5f) * g[c];
  float sh = be[c];
  float ss = 0.f;
  for (int r = 0; r < 64; ++r) {
    long i = (r0 + r) * O + c;
    float v = (h2f(y[i]) - mean) * sc + sh;
    v = fmaxf(v, 0.f);
    if (resid) v += h2f(resid[i]);
    ob[i] = f2h(v);
    ss += v;
  }
  if (ses) {
    int b = (r0 >= V_N) ? 1 : 0;
    atomicAdd(&ses[b * O + c], ss);
  }
}

// ---------- SE gate: sig[b,c] = sigmoid(W2 * relu(W1 * mean_v(out))), f32 weights ----------
__global__ void se_k(const float* __restrict__ ses, const float* __restrict__ w1,
                     const float* __restrict__ w2, float* __restrict__ sig)
{
  __shared__ float s[256];
  __shared__ float h[32];
  int b = blockIdx.x, t = threadIdx.x;
  s[t] = ses[b * 256 + t] * (1.f / 16384.f);
  __syncthreads();
  if (t < 32) {
    float a = 0.f;
    for (int c = 0; c < 256; ++c) a += w1[t * 256 + c] * s[c];
    h[t] = fmaxf(a, 0.f);
  }
  __syncthreads();
  float a = 0.f;
  #pragma unroll
  for (int r = 0; r < 32; ++r) a += w2[t * 32 + r] * h[r];
  sig[b * 256 + t] = 1.f / (1.f + expf(-a));
}

// ---------- x = out * sig (fp16 in/out, optional feat copy) ----------
__global__ __launch_bounds__(256) void scale_k(const u16* __restrict__ t, const float* __restrict__ sig,
                                               u16* __restrict__ xb, u16* __restrict__ fb)
{
  long i = ((long)blockIdx.x * 256 + threadIdx.x) * 4;
  int b = (int)(i >> 22);          // / (16384*256)
  int c = (int)(i & 255);
  uint2 pv = *(const uint2*)(t + i);
  const float* sg = sig + b * 256 + c;
  float v0 = h2f((u16)(pv.x & 0xffff)) * sg[0];
  float v1 = h2f((u16)(pv.x >> 16))    * sg[1];
  float v2 = h2f((u16)(pv.y & 0xffff)) * sg[2];
  float v3 = h2f((u16)(pv.y >> 16))    * sg[3];
  uint2 pk;
  pk.x = (unsigned)f2h(v0) | ((unsigned)f2h(v1) << 16);
  pk.y = (unsigned)f2h(v2) | ((unsigned)f2h(v3) << 16);
  *(uint2*)(xb + i) = pk;
  if (fb) *(uint2*)(fb + i) = pk;
}

// ---------- final 1-channel head: f32 weights/bias, f32 output ----------
__global__ __launch_bounds__(256) void cls3_k(const u16* __restrict__ h2, const float* __restrict__ w,
                                              const float* __restrict__ b, float* __restrict__ out)
{
  __shared__ float ws[64];
  int t = threadIdx.x;
  if (t < 64) ws[t] = w[t];
  __syncthreads();
  int r = blockIdx.x * 256 + t;
  const u16* p = h2 + (long)r * 64;
  float a = b[0];
  #pragma unroll
  for (int c = 0; c < 64; ++c) a += ws[c] * h2f(p[c]);
  out[r] = a;
}

extern "C" void kernel_launch(void* const* d_in, const int* in_sizes, int n_in,
                              void* d_out, int out_size, void* d_ws, size_t ws_size,
                              hipStream_t stream)
{
  (void)in_sizes; (void)n_in; (void)out_size; (void)ws_size;
  const float* verts   = (const float*)d_in[0];
  const int*   spirals = (const int*)d_in[1];
  const float* enc0_w  = (const float*)d_in[2];
  // conv biases before BN cancel exactly (BN subtracts per-channel mean): d_in[3],[7],[15],[19],[23] unused
  const float* enc0_g  = (const float*)d_in[4];
  const float* enc0_be = (const float*)d_in[5];
  const float* enc_w   = (const float*)d_in[6];
  const float* enc_g   = (const float*)d_in[8];
  const float* enc_be  = (const float*)d_in[9];
  const float* se_w1   = (const float*)d_in[10];
  const float* se_w2   = (const float*)d_in[11];
  const float* skip_w  = (const float*)d_in[12];
  const float* skip_b  = (const float*)d_in[13];
  const float* dec_w   = (const float*)d_in[14];
  const float* dec_g   = (const float*)d_in[16];
  const float* dec_be  = (const float*)d_in[17];
  const float* cls1_w  = (const float*)d_in[18];
  const float* cls1_g  = (const float*)d_in[20];
  const float* cls1_be = (const float*)d_in[21];
  const float* cls2_w  = (const float*)d_in[22];
  const float* cls2_g  = (const float*)d_in[24];
  const float* cls2_be = (const float*)d_in[25];
  const float* cls3_w  = (const float*)d_in[26];
  const float* cls3_b  = (const float*)d_in[27];

  // --- workspace (~94 MB): index-critical tables first ---
  char* p = (char*)d_ws;
  auto alloc = [&](size_t n) { char* q = p; p += (n + 255) & ~(size_t)255; return q; };
  int* ei[4];
  for (int i = 0; i < 4; ++i) ei[i] = (int*)alloc((size_t)V_N * 12 * 4);
  u16* wpe[6];
  for (int i = 0; i < 6; ++i) wpe[i] = (u16*)alloc((size_t)256 * 3072 * 2);
  u16* skip_wb = (u16*)alloc((size_t)3 * 256 * 512 * 2);
  u16* cls1_wb = (u16*)alloc((size_t)128 * 256 * 2);
  u16* wp6     = (u16*)alloc(128 * 128 * 2);
  float* stats = (float*)alloc(2048);   // [sum | sumsq]
  float* sesum = (float*)alloc(2048);   // contiguous after stats (one 4096B memset clears both)
  float* sig   = (float*)alloc(2048);
  u16* xb = (u16*)alloc((size_t)M_N * 256 * 2);
  u16* tb = (u16*)alloc((size_t)M_N * 256 * 2);
  u16* fb[3];
  for (int i = 0; i < 3; ++i) fb[i] = (u16*)alloc((size_t)M_N * 256 * 2);

  // prep (ws re-poisoned each call -> rebuild every launch)
  for (int s = 0; s < 4; ++s)
    eidx_k<<<768, 256, 0, stream>>>(spirals + (size_t)s * V_N * 12, ei[s]);
  for (int i = 0; i < 3; ++i) {
    perm_k<<<3072, 256, 0, stream>>>(enc_w + (size_t)i * 256 * 3072, wpe[i]);
    perm_k<<<3072, 256, 0, stream>>>(dec_w + (size_t)i * 256 * 3072, wpe[3 + i]);
  }
  cvt_k<<<1536, 256, 0, stream>>>(skip_w, skip_wb, 3 * 256 * 512);
  cvt_k<<<128, 256, 0, stream>>>(cls1_w, cls1_wb, 128 * 256);
  pad_k<<<64, 256, 0, stream>>>(cls2_w, wp6);

  auto bn = [&](const u16* yy, const float* g, const float* be, const u16* resid,
                u16* ob, float* ses, int O) {
    hipMemsetAsync(stats, 0, 4096, stream);   // clears stats + sesum
    stats_k<<<512, O, 0, stream>>>(yy, stats, O);
    bnrelu_k<<<512, O, 0, stream>>>(yy, stats, g, be, resid, ob, ses, O);
  };

  // ---- encoder block 0 ----
  enc0_k<<<1024, 256, 0, stream>>>(verts, ei[0], enc0_w, tb);
  bn(tb, enc0_g, enc0_be, nullptr, tb, sesum, 256);
  se_k<<<2, 256, 0, stream>>>(sesum, se_w1, se_w2, sig);
  scale_k<<<8192, 256, 0, stream>>>(tb, sig, xb, fb[0]);

  // ---- encoder blocks 1..3 ----
  for (int i = 1; i < 4; ++i) {
    gemm_k<<<dim3(256, 2), 256, 0, stream>>>(xb, nullptr, 256, ei[i], 12, 256,
                                             wpe[i - 1], 3072, tb, nullptr, 256);
    bn(tb, enc_g + (i - 1) * 256, enc_be + (i - 1) * 256, xb, tb, sesum, 256);
    se_k<<<2, 256, 0, stream>>>(sesum, se_w1 + (size_t)i * 32 * 256,
                                se_w2 + (size_t)i * 256 * 32, sig);
    scale_k<<<8192, 256, 0, stream>>>(tb, sig, xb, (i < 3) ? fb[i] : nullptr);
  }

  // ---- decoder blocks (feat buffer consumed by skip, then reused as conv-out) ----
  for (int i = 0; i < 3; ++i) {
    gemm_k<<<dim3(256, 2), 256, 0, stream>>>(xb, fb[2 - i], 256, nullptr, 2, 256,
                                             skip_wb + (size_t)i * 256 * 512, 512,
                                             tb, skip_b + i * 256, 256);          // x1 -> tb
    gemm_k<<<dim3(256, 2), 256, 0, stream>>>(tb, nullptr, 256, ei[2 - i], 12, 256,
                                             wpe[3 + i], 3072, fb[2 - i], nullptr, 256); // conv -> fb
    bn(fb[2 - i], dec_g + i * 256, dec_be + i * 256, tb, xb, nullptr, 256);       // x -> xb
  }

  // ---- classifier ----
  gemm_k<<<dim3(256, 1), 256, 0, stream>>>(xb, nullptr, 256, nullptr, 1, 256,
                                           cls1_wb, 256, tb, nullptr, 128);
  bn(tb, cls1_g, cls1_be, nullptr, tb, nullptr, 128);
  gemm_k<<<dim3(256, 1), 256, 0, stream>>>(tb, nullptr, 128, nullptr, 1, 128,
                                           wp6, 128, xb, nullptr, 64);
  bn(xb, cls2_g, cls2_be, nullptr, xb, nullptr, 64);
  cls3_k<<<128, 256, 0, stream>>>(xb, cls3_w, cls3_b, (float*)d_out);
}

// Round 5
// 1667.766 us; speedup vs baseline: 1.0146x; 1.0146x over previous
//
#include <hip/hip_runtime.h>

typedef unsigned short u16;
using f16x8 = __attribute__((ext_vector_type(8))) _Float16;  // 8 fp16 (4 VGPRs)
using f32x4 = __attribute__((ext_vector_type(4))) float;

#define V_N 16384
#define M_N 32768

__device__ __forceinline__ float h2f(u16 u) {
  _Float16 h; __builtin_memcpy(&h, &u, 2); return (float)h;
}
__device__ __forceinline__ u16 f2h(float f) {
  _Float16 h = (_Float16)f; u16 u; __builtin_memcpy(&u, &h, 2); return u;
}

// ---------- prep kernels ----------
// wp[o][t*256+c] = f2h(w[o][c*12+t])   (l-major K permutation, f32 -> fp16)
__global__ __launch_bounds__(256) void perm_k(const float* __restrict__ w, u16* __restrict__ wp) {
  int i = blockIdx.x * 256 + threadIdx.x;            // 256*3072
  int o = i / 3072, k = i - o * 3072;
  int t = k >> 8, c = k & 255;
  wp[i] = f2h(w[o * 3072 + c * 12 + t]);
}

// flat f32 -> fp16 convert
__global__ __launch_bounds__(256) void cvt_k(const float* __restrict__ w, u16* __restrict__ wb, int n) {
  int i = blockIdx.x * 256 + threadIdx.x;
  if (i < n) wb[i] = f2h(w[i]);
}

// cls2_w (64x128 f32) -> zero-padded 128x128 fp16
__global__ __launch_bounds__(256) void pad_k(const float* __restrict__ w, u16* __restrict__ wp) {
  int i = blockIdx.x * 256 + threadIdx.x;            // 128*128
  wp[i] = (i < 8192) ? f2h(w[i]) : (u16)0;
}

// ---------- encoder block 0 conv (C_in=3, K=36), f32 in -> fp16 out ----------
// neighbor index: j(v,t) = sp[t*V + v]  (validated reshape-scrambled layout)
__global__ __launch_bounds__(256) void enc0_k(const float* __restrict__ verts, const int* __restrict__ sp,
                                              const float* __restrict__ w0, u16* __restrict__ y) {
  __shared__ float xs[32][36];
  int t = threadIdx.x;
  int r0 = blockIdx.x * 32;
  for (int s = t; s < 32 * 12; s += 256) {
    int row = s / 12, tt = s - row * 12;
    int gr = r0 + row;
    int b = gr >> 14, v = gr & (V_N - 1);
    int j = sp[tt * V_N + v];
    const float* p = verts + ((long)b * V_N + j) * 3;
    xs[row][tt]      = p[0];
    xs[row][12 + tt] = p[1];
    xs[row][24 + tt] = p[2];
  }
  __syncthreads();
  float w[36];
  #pragma unroll
  for (int k = 0; k < 36; ++k) w[k] = w0[t * 36 + k];
  for (int row = 0; row < 32; ++row) {
    float a = 0.f;
    #pragma unroll
    for (int k = 0; k < 36; ++k) a += w[k] * xs[row][k];
    y[(long)(r0 + row) * 256 + t] = f2h(a);
  }
}

// ---------- LDS-free, barrier-free MFMA GEMM ----------
// Y[M x Ostore](fp16) = gatherA[M x (L*C)] * Wt^T (+f32 bias), optional per-channel
// stats (sum at stats[col], sumsq at stats[Ostore+col]).
// Gather: row = b*V + sp[l*V + v] (sp!=null) else global row; A source P0 for l==0,
// P1 for l>=1 (concat trick). Wt: fp16 [o][l*C+c], row stride ldw.
// Block 256 thr = 4 waves, each wave a 64x64 tile; block tile 128x128.
// Both MFMA operands loaded straight from global (16B/lane), 1-deep ping-pong pipeline.
__global__ __launch_bounds__(256) void gemm_k(
    const u16* __restrict__ P0, const u16* __restrict__ P1, int lda,
    const int* __restrict__ sp, int L, int C,
    const u16* __restrict__ Wt, int ldw,
    u16* __restrict__ Yb, const float* __restrict__ bias, int Ostore,
    float* __restrict__ stats)
{
  int tid  = threadIdx.x;
  int bm = blockIdx.x * 128, bn = blockIdx.y * 128;
  int wave = tid >> 6, lane = tid & 63;
  int wm = (wave & 1) * 64, wn = (wave >> 1) * 64;
  int lr = lane & 15, lq = lane >> 4;
  const int KC = C >> 5;                         // K-chunks (of 32) per l; always even

  // B fragment row pointers (lq*8 k-offset folded in)
  const u16* bp[4];
  #pragma unroll
  for (int nt = 0; nt < 4; ++nt)
    bp[nt] = Wt + (long)(bn + wn + nt * 16 + lr) * ldw + lq * 8;

  const bool gat = (sp != nullptr);
  const long bbase = (bm >= V_N) ? (long)V_N * lda : 0;   // batch element offset
  const int vb = (bm & (V_N - 1)) + wm + lr;              // + mt*16

  f32x4 acc[4][4];
  #pragma unroll
  for (int i = 0; i < 4; ++i)
    #pragma unroll
    for (int j = 0; j < 4; ++j) acc[i][j] = (f32x4){0.f, 0.f, 0.f, 0.f};

  long ao[4], aon[4];
  int idxn[4];
  const u16* as0 = P0;

  if (gat) {
    int idx0[4];
    #pragma unroll
    for (int mt = 0; mt < 4; ++mt) idx0[mt] = sp[vb + mt * 16];
    #pragma unroll
    for (int mt = 0; mt < 4; ++mt) ao[mt] = bbase + (long)idx0[mt] * lda + lq * 8;
  } else {
    #pragma unroll
    for (int mt = 0; mt < 4; ++mt) ao[mt] = (long)(bm + wm + mt * 16 + lr) * lda + lq * 8;
  }

  f16x8 fa0[4], fb0[4], fa1[4], fb1[4];
  // fetch (l=0, kc=0) -> buf0
  #pragma unroll
  for (int mt = 0; mt < 4; ++mt) fa0[mt] = *(const f16x8*)(as0 + ao[mt]);
  #pragma unroll
  for (int nt = 0; nt < 4; ++nt) fb0[nt] = *(const f16x8*)(bp[nt]);
  // prefetch gather indices for l=1
  if (gat && L > 1) {
    #pragma unroll
    for (int mt = 0; mt < 4; ++mt) idxn[mt] = sp[V_N + vb + mt * 16];
  }

  for (int l = 0; l < L; ++l) {
    const bool hasN = (l + 1 < L);
    const u16* asn = gat ? P0 : ((P1 != nullptr) ? P1 : P0);   // direct: l>=1 reads P1
    const long bko = (long)l * C;
    for (int kc = 0; kc < KC; kc += 2) {
      {  // buf0 = (l,kc): prefetch (l,kc+1) -> buf1
        int ak = (kc + 1) * 32;
        long bk = bko + ak;
        #pragma unroll
        for (int mt = 0; mt < 4; ++mt) fa1[mt] = *(const f16x8*)(as0 + ao[mt] + ak);
        #pragma unroll
        for (int nt = 0; nt < 4; ++nt) fb1[nt] = *(const f16x8*)(bp[nt] + bk);
      }
      #pragma unroll
      for (int mt = 0; mt < 4; ++mt)
        #pragma unroll
        for (int nt = 0; nt < 4; ++nt)
          acc[mt][nt] = __builtin_amdgcn_mfma_f32_16x16x32_f16(fa0[mt], fb0[nt], acc[mt][nt], 0, 0, 0);
      // buf1 = (l,kc+1): prefetch successor -> buf0
      if (kc + 2 < KC) {
        int ak = (kc + 2) * 32;
        long bk = bko + ak;
        #pragma unroll
        for (int mt = 0; mt < 4; ++mt) fa0[mt] = *(const f16x8*)(as0 + ao[mt] + ak);
        #pragma unroll
        for (int nt = 0; nt < 4; ++nt) fb0[nt] = *(const f16x8*)(bp[nt] + bk);
      } else if (hasN) {
        if (gat) {
          #pragma unroll
          for (int mt = 0; mt < 4; ++mt) aon[mt] = bbase + (long)idxn[mt] * lda + lq * 8;
        } else {
          #pragma unroll
          for (int mt = 0; mt < 4; ++mt) aon[mt] = ao[mt];
        }
        long bk = bko + C;
        #pragma unroll
        for (int mt = 0; mt < 4; ++mt) fa0[mt] = *(const f16x8*)(asn + aon[mt]);
        #pragma unroll
        for (int nt = 0; nt < 4; ++nt) fb0[nt] = *(const f16x8*)(bp[nt] + bk);
      }
      #pragma unroll
      for (int mt = 0; mt < 4; ++mt)
        #pragma unroll
        for (int nt = 0; nt < 4; ++nt)
          acc[mt][nt] = __builtin_amdgcn_mfma_f32_16x16x32_f16(fa1[mt], fb1[nt], acc[mt][nt], 0, 0, 0);
    }
    if (hasN) {
      #pragma unroll
      for (int mt = 0; mt < 4; ++mt) ao[mt] = aon[mt];
      as0 = asn;
      if (gat && l + 2 < L) {
        #pragma unroll
        for (int mt = 0; mt < 4; ++mt) idxn[mt] = sp[(long)(l + 2) * V_N + vb + mt * 16];
      }
    }
  }

  // epilogue: C/D layout col=lane&15, row=(lane>>4)*4+reg [guide m89]; fused BN-stats
  #pragma unroll
  for (int nt = 0; nt < 4; ++nt) {
    int col = bn + wn + nt * 16 + lr;
    if (col < Ostore) {
      float bv = bias ? bias[col] : 0.f;
      float s1 = 0.f, s2 = 0.f;
      #pragma unroll
      for (int mt = 0; mt < 4; ++mt) {
        #pragma unroll
        for (int rg = 0; rg < 4; ++rg) {
          int row = bm + wm + mt * 16 + lq * 4 + rg;
          float v = acc[mt][nt][rg] + bv;
          Yb[(long)row * Ostore + col] = f2h(v);
          s1 += v; s2 += v * v;
        }
      }
      if (stats) {
        s1 += __shfl_xor(s1, 16); s1 += __shfl_xor(s1, 32);   // reduce over lq (same col)
        s2 += __shfl_xor(s2, 16); s2 += __shfl_xor(s2, 32);
        if (lq == 0) {
          atomicAdd(&stats[col], s1);
          atomicAdd(&stats[Ostore + col], s2);
        }
      }
    }
  }
}

// ---------- stats for enc0 output (O=256), vectorized ----------
__global__ __launch_bounds__(256) void stats2_k(const u16* __restrict__ y, float* __restrict__ st) {
  __shared__ float s1L[256], s2L[256];
  int tid = threadIdx.x;
  int ci = (tid & 63) * 4;
  int r0 = blockIdx.x * 64 + (tid >> 6);
  float a1[4] = {0,0,0,0}, a2[4] = {0,0,0,0};
  for (int it = 0; it < 16; ++it) {
    long i = ((long)r0 + it * 4) * 256 + ci;
    uint2 pv = *(const uint2*)(y + i);
    float v0 = h2f((u16)(pv.x & 0xffff)), v1 = h2f((u16)(pv.x >> 16));
    float v2 = h2f((u16)(pv.y & 0xffff)), v3 = h2f((u16)(pv.y >> 16));
    a1[0] += v0; a1[1] += v1; a1[2] += v2; a1[3] += v3;
    a2[0] += v0*v0; a2[1] += v1*v1; a2[2] += v2*v2; a2[3] += v3*v3;
  }
  s1L[tid] = 0.f; s2L[tid] = 0.f;
  __syncthreads();
  #pragma unroll
  for (int j = 0; j < 4; ++j) { atomicAdd(&s1L[ci + j], a1[j]); atomicAdd(&s2L[ci + j], a2[j]); }
  __syncthreads();
  atomicAdd(&st[tid], s1L[tid]);
  atomicAdd(&st[256 + tid], s2L[tid]);
}

// ---------- vectorized BN+ReLU (+fp16 residual) (+SE channel sums via LDS) ----------
// grid = 2*O blocks of 256 threads; O in {64,128,256} (power of 2)
__global__ __launch_bounds__(256) void bnrelu2_k(
    const u16* __restrict__ y, const float* __restrict__ st,
    const float* __restrict__ g, const float* __restrict__ be,
    const u16* __restrict__ resid, u16* __restrict__ ob,
    float* __restrict__ ses, int O)
{
  __shared__ float sL[256];
  int tid = threadIdx.x;
  int tpr = O >> 2;                       // threads per row
  int rpi = 256 / tpr;                    // rows per iteration
  int ci = (tid & (tpr - 1)) * 4;
  int r0 = blockIdx.x * (rpi * 16) + (tid / tpr);
  float mean[4], sc[4], sh[4];
  #pragma unroll
  for (int j = 0; j < 4; ++j) {
    int c = ci + j;
    float m = st[c] * (1.f / 32768.f);
    float var = st[O + c] * (1.f / 32768.f) - m * m;
    mean[j] = m;
    sc[j] = rsqrtf(fmaxf(var, 0.f) + 1e-5f) * g[c];
    sh[j] = be[c];
  }
  float ss[4] = {0,0,0,0};
  for (int it = 0; it < 16; ++it) {
    long i = ((long)r0 + (long)it * rpi) * O + ci;
    uint2 pv = *(const uint2*)(y + i);
    float v[4];
    v[0] = fmaxf((h2f((u16)(pv.x & 0xffff)) - mean[0]) * sc[0] + sh[0], 0.f);
    v[1] = fmaxf((h2f((u16)(pv.x >> 16))    - mean[1]) * sc[1] + sh[1], 0.f);
    v[2] = fmaxf((h2f((u16)(pv.y & 0xffff)) - mean[2]) * sc[2] + sh[2], 0.f);
    v[3] = fmaxf((h2f((u16)(pv.y >> 16))    - mean[3]) * sc[3] + sh[3], 0.f);
    if (resid) {
      uint2 rv = *(const uint2*)(resid + i);
      v[0] += h2f((u16)(rv.x & 0xffff)); v[1] += h2f((u16)(rv.x >> 16));
      v[2] += h2f((u16)(rv.y & 0xffff)); v[3] += h2f((u16)(rv.y >> 16));
    }
    uint2 pk;
    pk.x = (unsigned)f2h(v[0]) | ((unsigned)f2h(v[1]) << 16);
    pk.y = (unsigned)f2h(v[2]) | ((unsigned)f2h(v[3]) << 16);
    *(uint2*)(ob + i) = pk;
    #pragma unroll
    for (int j = 0; j < 4; ++j) ss[j] += v[j];
  }
  if (ses) {                              // O==256 path: block spans 64 rows, single batch
    sL[tid] = 0.f;
    __syncthreads();
    #pragma unroll
    for (int j = 0; j < 4; ++j) atomicAdd(&sL[ci + j], ss[j]);
    __syncthreads();
    int b = (blockIdx.x * (rpi * 16)) >= V_N;
    atomicAdd(&ses[b * O + tid], sL[tid]);
  }
}

// ---------- SE gate: sig[b,c] = sigmoid(W2 * relu(W1 * mean_v(out))), f32 weights ----------
__global__ void se_k(const float* __restrict__ ses, const float* __restrict__ w1,
                     const float* __restrict__ w2, float* __restrict__ sig)
{
  __shared__ float s[256];
  __shared__ float h[32];
  int b = blockIdx.x, t = threadIdx.x;
  s[t] = ses[b * 256 + t] * (1.f / 16384.f);
  __syncthreads();
  if (t < 32) {
    float a = 0.f;
    for (int c = 0; c < 256; ++c) a += w1[t * 256 + c] * s[c];
    h[t] = fmaxf(a, 0.f);
  }
  __syncthreads();
  float a = 0.f;
  #pragma unroll
  for (int r = 0; r < 32; ++r) a += w2[t * 32 + r] * h[r];
  sig[b * 256 + t] = 1.f / (1.f + expf(-a));
}

// ---------- x = out * sig (fp16 in/out, optional feat copy) ----------
__global__ __launch_bounds__(256) void scale_k(const u16* __restrict__ t, const float* __restrict__ sig,
                                               u16* __restrict__ xb, u16* __restrict__ fb)
{
  long i = ((long)blockIdx.x * 256 + threadIdx.x) * 4;
  int b = (int)(i >> 22);          // / (16384*256)
  int c = (int)(i & 255);
  uint2 pv = *(const uint2*)(t + i);
  const float* sg = sig + b * 256 + c;
  float v0 = h2f((u16)(pv.x & 0xffff)) * sg[0];
  float v1 = h2f((u16)(pv.x >> 16))    * sg[1];
  float v2 = h2f((u16)(pv.y & 0xffff)) * sg[2];
  float v3 = h2f((u16)(pv.y >> 16))    * sg[3];
  uint2 pk;
  pk.x = (unsigned)f2h(v0) | ((unsigned)f2h(v1) << 16);
  pk.y = (unsigned)f2h(v2) | ((unsigned)f2h(v3) << 16);
  *(uint2*)(xb + i) = pk;
  if (fb) *(uint2*)(fb + i) = pk;
}

// ---------- final 1-channel head: f32 weights/bias, f32 output ----------
__global__ __launch_bounds__(256) void cls3_k(const u16* __restrict__ h2, const float* __restrict__ w,
                                              const float* __restrict__ b, float* __restrict__ out)
{
  __shared__ float ws[64];
  int t = threadIdx.x;
  if (t < 64) ws[t] = w[t];
  __syncthreads();
  int r = blockIdx.x * 256 + t;
  const u16* p = h2 + (long)r * 64;
  float a = b[0];
  #pragma unroll
  for (int c = 0; c < 64; ++c) a += ws[c] * h2f(p[c]);
  out[r] = a;
}

extern "C" void kernel_launch(void* const* d_in, const int* in_sizes, int n_in,
                              void* d_out, int out_size, void* d_ws, size_t ws_size,
                              hipStream_t stream)
{
  (void)in_sizes; (void)n_in; (void)out_size; (void)ws_size;
  const float* verts   = (const float*)d_in[0];
  const int*   spirals = (const int*)d_in[1];
  const float* enc0_w  = (const float*)d_in[2];
  // conv biases before BN cancel exactly (BN subtracts per-channel mean): d_in[3],[7],[15],[19],[23] unused
  const float* enc0_g  = (const float*)d_in[4];
  const float* enc0_be = (const float*)d_in[5];
  const float* enc_w   = (const float*)d_in[6];
  const float* enc_g   = (const float*)d_in[8];
  const float* enc_be  = (const float*)d_in[9];
  const float* se_w1   = (const float*)d_in[10];
  const float* se_w2   = (const float*)d_in[11];
  const float* skip_w  = (const float*)d_in[12];
  const float* skip_b  = (const float*)d_in[13];
  const float* dec_w   = (const float*)d_in[14];
  const float* dec_g   = (const float*)d_in[16];
  const float* dec_be  = (const float*)d_in[17];
  const float* cls1_w  = (const float*)d_in[18];
  const float* cls1_g  = (const float*)d_in[20];
  const float* cls1_be = (const float*)d_in[21];
  const float* cls2_w  = (const float*)d_in[22];
  const float* cls2_g  = (const float*)d_in[24];
  const float* cls2_be = (const float*)d_in[25];
  const float* cls3_w  = (const float*)d_in[26];
  const float* cls3_b  = (const float*)d_in[27];

  // --- workspace (~92 MB) ---
  char* p = (char*)d_ws;
  auto alloc = [&](size_t n) { char* q = p; p += (n + 255) & ~(size_t)255; return q; };
  u16* wpe[6];
  for (int i = 0; i < 6; ++i) wpe[i] = (u16*)alloc((size_t)256 * 3072 * 2);
  u16* skip_wb = (u16*)alloc((size_t)3 * 256 * 512 * 2);
  u16* cls1_wb = (u16*)alloc((size_t)128 * 256 * 2);
  u16* wp6     = (u16*)alloc(128 * 128 * 2);
  float* stats = (float*)alloc(2048);   // [sum | sumsq]
  float* sesum = (float*)alloc(2048);   // contiguous after stats (one 4096B memset clears both)
  float* sig   = (float*)alloc(2048);
  u16* xb = (u16*)alloc((size_t)M_N * 256 * 2);
  u16* tb = (u16*)alloc((size_t)M_N * 256 * 2);
  u16* fb[3];
  for (int i = 0; i < 3; ++i) fb[i] = (u16*)alloc((size_t)M_N * 256 * 2);

  // prep (ws re-poisoned each call -> rebuild every launch)
  for (int i = 0; i < 3; ++i) {
    perm_k<<<3072, 256, 0, stream>>>(enc_w + (size_t)i * 256 * 3072, wpe[i]);
    perm_k<<<3072, 256, 0, stream>>>(dec_w + (size_t)i * 256 * 3072, wpe[3 + i]);
  }
  cvt_k<<<1536, 256, 0, stream>>>(skip_w, skip_wb, 3 * 256 * 512);
  cvt_k<<<128, 256, 0, stream>>>(cls1_w, cls1_wb, 128 * 256);
  pad_k<<<64, 256, 0, stream>>>(cls2_w, wp6);

  // ---- encoder block 0 ----
  hipMemsetAsync(stats, 0, 4096, stream);   // clears stats + sesum
  enc0_k<<<1024, 256, 0, stream>>>(verts, spirals, enc0_w, tb);
  stats2_k<<<512, 256, 0, stream>>>(tb, stats);
  bnrelu2_k<<<512, 256, 0, stream>>>(tb, stats, enc0_g, enc0_be, nullptr, tb, sesum, 256);
  se_k<<<2, 256, 0, stream>>>(sesum, se_w1, se_w2, sig);
  scale_k<<<8192, 256, 0, stream>>>(tb, sig, xb, fb[0]);

  // ---- encoder blocks 1..3 ----
  for (int i = 1; i < 4; ++i) {
    hipMemsetAsync(stats, 0, 4096, stream);
    gemm_k<<<dim3(256, 2), 256, 0, stream>>>(xb, nullptr, 256,
                                             spirals + (size_t)i * V_N * 12, 12, 256,
                                             wpe[i - 1], 3072, tb, nullptr, 256, stats);
    bnrelu2_k<<<512, 256, 0, stream>>>(tb, stats, enc_g + (i - 1) * 256, enc_be + (i - 1) * 256,
                                       xb, tb, sesum, 256);
    se_k<<<2, 256, 0, stream>>>(sesum, se_w1 + (size_t)i * 32 * 256,
                                se_w2 + (size_t)i * 256 * 32, sig);
    scale_k<<<8192, 256, 0, stream>>>(tb, sig, xb, (i < 3) ? fb[i] : nullptr);
  }

  // ---- decoder blocks (feat buffer consumed by skip, then reused as conv-out) ----
  for (int i = 0; i < 3; ++i) {
    gemm_k<<<dim3(256, 2), 256, 0, stream>>>(xb, fb[2 - i], 256, nullptr, 2, 256,
                                             skip_wb + (size_t)i * 256 * 512, 512,
                                             tb, skip_b + i * 256, 256, nullptr);   // x1 -> tb
    hipMemsetAsync(stats, 0, 4096, stream);
    gemm_k<<<dim3(256, 2), 256, 0, stream>>>(tb, nullptr, 256,
                                             spirals + (size_t)(2 - i) * V_N * 12, 12, 256,
                                             wpe[3 + i], 3072, fb[2 - i], nullptr, 256, stats);
    bnrelu2_k<<<512, 256, 0, stream>>>(fb[2 - i], stats, dec_g + i * 256, dec_be + i * 256,
                                       tb, xb, nullptr, 256);                       // x -> xb
  }

  // ---- classifier ----
  hipMemsetAsync(stats, 0, 4096, stream);
  gemm_k<<<dim3(256, 1), 256, 0, stream>>>(xb, nullptr, 256, nullptr, 1, 256,
                                           cls1_wb, 256, tb, nullptr, 128, stats);
  bnrelu2_k<<<256, 256, 0, stream>>>(tb, stats, cls1_g, cls1_be, nullptr, tb, nullptr, 128);
  hipMemsetAsync(stats, 0, 4096, stream);
  gemm_k<<<dim3(256, 1), 256, 0, stream>>>(tb, nullptr, 128, nullptr, 1, 128,
                                           wp6, 128, xb, nullptr, 64, stats);
  bnrelu2_k<<<128, 256, 0, stream>>>(xb, stats, cls2_g, cls2_be, nullptr, xb, nullptr, 64);
  cls3_k<<<128, 256, 0, stream>>>(xb, cls3_w, cls3_b, (float*)d_out);
}